// Round 2
// baseline (373.280 us; speedup 1.0000x reference)
//
#include <hip/hip_runtime.h>
#include <hip/hip_bf16.h>

// Static config: B=32, H=96, Wd=96, C=64, nW=4, K=3, WS=48, pool=16
#define NPIX 9216   // 96*96

__device__ __forceinline__ float geluf(float x){
  return 0.5f * x * (1.0f + erff(x * 0.70710678118654752440f));
}
__device__ __forceinline__ float sigm(float x){
  return 1.0f / (1.0f + expf(-x));
}

// ---------------------------------------------------------------------------
// Kernel A: windowed 48x48 -> 3x3 avg pool.  kern[bw=b*4+w][c][ki*3+kj]
// grid = 128 * 9 = 1152 blocks, 256 threads
// ---------------------------------------------------------------------------
__global__ __launch_bounds__(256) void k_pool(const float* __restrict__ x,
                                              float* __restrict__ kern)
{
  int blk = blockIdx.x;
  int bw = blk / 9, rem = blk % 9;          // rem = ki*3+kj
  int ki = rem / 3, kj = rem % 3;
  int b = bw >> 2, w = bw & 3;
  int wr = w >> 1, wc = w & 1;
  int t = threadIdx.x;
  int cg = t & 15, rw = t >> 4;             // cg: 4-channel group, rw: row 0..15
  int h = wr*48 + ki*16 + rw;
  int col0 = wc*48 + kj*16;
  size_t base = ((size_t)(b*NPIX + h*96 + col0))*64 + cg*4;
  float a0=0.f,a1=0.f,a2=0.f,a3=0.f;
  #pragma unroll
  for (int j=0;j<16;j++){
    float4 u = *(const float4*)(x + base + (size_t)j*64);
    a0 += u.x; a1 += u.y; a2 += u.z; a3 += u.w;
  }
  __shared__ float red[16*64];
  float* rr = &red[rw*64 + cg*4];
  rr[0]=a0; rr[1]=a1; rr[2]=a2; rr[3]=a3;
  __syncthreads();
  if (t < 64){
    float s = 0.f;
    #pragma unroll
    for (int r=0;r<16;r++) s += red[r*64 + t];
    kern[(size_t)bw*576 + t*9 + rem] = s * (1.0f/256.0f);
  }
}

// ---------------------------------------------------------------------------
// Kernel B: entire small graph per batch element -> combined 3x3 kernel
// kc[b][c][p] = 2*gkf + fu_po(x_sum).  grid = 32 blocks, 256 threads
// ---------------------------------------------------------------------------
__global__ __launch_bounds__(256) void k_small(const float* __restrict__ kern_ws,
    const float* __restrict__ se_w1, const float* __restrict__ se_b1,
    const float* __restrict__ se_w2, const float* __restrict__ se_b2,
    const float* __restrict__ dc_w,  const float* __restrict__ dc_b,
    const float* __restrict__ l1_w,  const float* __restrict__ l1_b,
    const float* __restrict__ l2_w,  const float* __restrict__ l2_b,
    const float* __restrict__ gkf_w, const float* __restrict__ gkf_b,
    const float* __restrict__ fu_proj_w, const float* __restrict__ fu_proj_b,
    const float* __restrict__ fu_fc1_w,  const float* __restrict__ fu_fc1_b,
    const float* __restrict__ fu_fc2_w,  const float* __restrict__ fu_fc2_b,
    const float* __restrict__ fu_po_w,   const float* __restrict__ fu_po_b,
    float* __restrict__ kc_ws)
{
  int b = blockIdx.x;
  int t = threadIdx.x;
  __shared__ float s_kern[4*64*9];   // [w][c][p]
  __shared__ float s_w[4096];        // transposed weight staging [i][o]
  __shared__ float s_tmp[4*64*9];    // gelu intermediate, later feats [g][o][p]
  __shared__ float s_kse[4*64*9];    // kern_se [w][c][p]
  __shared__ float s_wwc[256];       // [w][c]
  __shared__ float s_small[64];      // ww1(0..3), h1(16..31), ww2(32..35)
  __shared__ float s_gkf[576];       // [c][p]
  __shared__ float s_v0[256];
  __shared__ float s_v1[64];
  __shared__ float s_av[256];        // [w][c]
  __shared__ float s_xsum[576];      // [c][p]

  for (int idx=t; idx<2304; idx+=256) s_kern[idx] = kern_ws[b*2304 + idx];
  for (int idx=t; idx<4096; idx+=256){ int o=idx>>6, i=idx&63; s_w[i*64+o] = se_w1[idx]; }
  __syncthreads();
  // SE layer 1: gelu(W1 @ kern + b1)
  for (int idx=t; idx<2304; idx+=256){
    int w = idx/576, rem = idx%576, o = rem/9, p = rem%9;
    float acc = se_b1[o];
    const float* kcol = &s_kern[w*576 + p];
    #pragma unroll 8
    for (int i=0;i<64;i++) acc += s_w[i*64+o]*kcol[i*9];
    s_tmp[idx] = geluf(acc);
  }
  __syncthreads();
  for (int idx=t; idx<4096; idx+=256){ int o=idx>>6, i=idx&63; s_w[i*64+o] = se_w2[idx]; }
  __syncthreads();
  // SE layer 2: sigmoid(W2 @ g + b2) -> kern_se
  for (int idx=t; idx<2304; idx+=256){
    int w = idx/576, rem = idx%576, o = rem/9, p = rem%9;
    float acc = se_b2[o];
    const float* gcol = &s_tmp[w*576 + p];
    #pragma unroll 8
    for (int i=0;i<64;i++) acc += s_w[i*64+o]*gcol[i*9];
    s_kse[idx] = sigm(acc);
  }
  __syncthreads();
  // window GAP == mean of the 9 kern entries (exact: pooling partitions window)
  { int w = t>>6, c = t&63; float s=0.f;
    #pragma unroll
    for (int p=0;p<9;p++) s += s_kern[w*576+c*9+p];
    s_wwc[t] = s*(1.0f/9.0f); }
  __syncthreads();
  if (t<4){ float acc = dc_b[t];
    for (int c=0;c<64;c++) acc += dc_w[t*64+c]*s_wwc[t*64+c];
    s_small[t]=acc; }
  __syncthreads();
  if (t<16){ float acc = l1_b[t];
    #pragma unroll
    for (int w=0;w<4;w++) acc += l1_w[t*4+w]*s_small[w];
    s_small[16+t]=geluf(acc); }
  __syncthreads();
  if (t<4){ float acc = l2_b[t];
    #pragma unroll
    for (int j=0;j<16;j++) acc += l2_w[t*16+j]*s_small[16+j];
    s_small[32+t]=sigm(acc); }
  __syncthreads();
  // gkf[c][p] = gkf_b[c] + sum_w gkf_w[c][w] * kse[w][c][p] * ww2[w]
  for (int idx=t; idx<576; idx+=256){
    int c = idx/9, p = idx%9;
    float acc = gkf_b[c];
    #pragma unroll
    for (int w=0;w<4;w++) acc += gkf_w[c*4+w]*s_kse[w*576+c*9+p]*s_small[32+w];
    s_gkf[idx] = acc;
  }
  // feats[g][o][p] = gelu(proj_b[g*4+o] + sum_i proj_w[g][o][i]*kse_flat[g*4+i][p])
  for (int idx=t; idx<2304; idx+=256){
    int g = idx/36, rem = idx%36, o = rem/9, p = rem%9;
    float acc = fu_proj_b[g*4+o];
    #pragma unroll
    for (int i=0;i<4;i++){
      int ch = g*4+i;                       // flat channel in (w*C + c) layout
      acc += fu_proj_w[(g*4+o)*4+i] * s_kse[(ch>>6)*576 + (ch&63)*9 + p];
    }
    s_tmp[idx] = geluf(acc);
  }
  __syncthreads();
  // v0[m] = mean_p feats   (idx = (m>>2)*36 + (m&3)*9 + p == m*9+p)
  { float s=0.f;
    #pragma unroll
    for (int p=0;p<9;p++) s += s_tmp[t*9+p];
    s_v0[t] = s*(1.0f/9.0f); }
  __syncthreads();
  if (t<64){ float acc = fu_fc1_b[t];
    for (int k=0;k<256;k++) acc += fu_fc1_w[t*256+k]*s_v0[k];
    s_v1[t]=geluf(acc); }
  __syncthreads();
  { float acc = fu_fc2_b[t];
    #pragma unroll 8
    for (int o2=0;o2<64;o2++) acc += fu_fc2_w[t*64+o2]*s_v1[o2];
    s_av[t]=acc; }
  __syncthreads();
  if (t<64){
    float z0=s_av[t], z1=s_av[64+t], z2=s_av[128+t], z3=s_av[192+t];
    float mx = fmaxf(fmaxf(z0,z1),fmaxf(z2,z3));
    float e0=expf(z0-mx), e1=expf(z1-mx), e2=expf(z2-mx), e3=expf(z3-mx);
    float inv = 1.0f/(e0+e1+e2+e3);
    s_av[t]=e0*inv; s_av[64+t]=e1*inv; s_av[128+t]=e2*inv; s_av[192+t]=e3*inv;
  }
  __syncthreads();
  for (int idx=t; idx<576; idx+=256){
    int c=idx/9, p=idx%9; float s=0.f;
    #pragma unroll
    for (int w=0;w<4;w++) s += s_kse[w*576+c*9+p]*s_av[w*64+c];
    s_xsum[idx]=s;
  }
  __syncthreads();
  // combined kernel kc = gkf + gks = 2*gkf + fu_po_w @ x_sum + fu_po_b
  for (int idx=t; idx<576; idx+=256){
    int c=idx/9, p=idx%9;
    float acc = 2.0f*s_gkf[idx] + fu_po_b[c];
    #pragma unroll 8
    for (int i=0;i<64;i++) acc += fu_po_w[c*64+i]*s_xsum[i*9+p];
    kc_ws[b*576+idx] = acc;
  }
}

// ---------------------------------------------------------------------------
// Kernel C: depthwise 3x3 (per b,c kernel kc) + 64x64 conv1x1 epilogue
// grid = 32 * 144 = 4608 blocks (8x8 pixel tile each), 256 threads
// ---------------------------------------------------------------------------
__global__ __launch_bounds__(256) void k_conv(const float* __restrict__ x,
                                              const float* __restrict__ kc_ws,
                                              const float* __restrict__ po_w,
                                              const float* __restrict__ po_b,
                                              float* __restrict__ out)
{
  int bi = blockIdx.x;
  int b = bi / 144, tile = bi % 144;
  int th = tile / 12, tw = tile % 12;
  int h0 = th*8, w0 = tw*8;
  int t = threadIdx.x;

  __shared__ float s_x[100*64];   // halo tile [r*10+col][c]
  __shared__ float s_kc[576];     // [c][p]
  __shared__ float s_pw[64*65];   // po_w transposed [c][o], pad 65 (conflict-free)
  __shared__ float s_tmp[64*64];  // depthwise result [pix][c]

  // stage x halo tile (10x10 pixels, zero-padded at image edges)
  for (int idx=t; idx<1600; idx+=256){
    int pix = idx >> 4, c4 = idx & 15;          // 16 float4 chunks per pixel
    int r = pix / 10, col = pix % 10;
    int hh = h0 - 1 + r, ww = w0 - 1 + col;
    float4 v = make_float4(0.f,0.f,0.f,0.f);
    if (hh >= 0 && hh < 96 && ww >= 0 && ww < 96)
      v = *(const float4*)(x + (((size_t)b*NPIX + hh*96 + ww)<<6) + c4*4);
    *(float4*)&s_x[pix*64 + c4*4] = v;
  }
  for (int idx=t; idx<576; idx+=256) s_kc[idx] = kc_ws[b*576 + idx];
  for (int idx=t; idx<4096; idx+=256){ int o = idx>>6, c = idx&63; s_pw[c*65+o] = po_w[idx]; }
  __syncthreads();

  // phase 1: depthwise 3x3 -> s_tmp[pix][c]
  {
    int c = t & 63, pg = t >> 6;
    float k0=s_kc[c*9+0],k1=s_kc[c*9+1],k2=s_kc[c*9+2],
          k3=s_kc[c*9+3],k4=s_kc[c*9+4],k5=s_kc[c*9+5],
          k6=s_kc[c*9+6],k7=s_kc[c*9+7],k8=s_kc[c*9+8];
    #pragma unroll
    for (int pp=0; pp<16; pp++){
      int pix = pg*16 + pp;
      int pr = pix >> 3, pc = pix & 7;
      const float* xc = &s_x[(pr*10 + pc)*64 + c];
      float acc = k0*xc[0]    + k1*xc[64]   + k2*xc[128]
                + k3*xc[640]  + k4*xc[704]  + k5*xc[768]
                + k6*xc[1280] + k7*xc[1344] + k8*xc[1408];
      s_tmp[pix*64 + c] = acc;
    }
  }
  __syncthreads();

  // phase 2: out[pix][o] = sum_c po_w[o][c]*tmp[pix][c] + po_b[o]
  {
    int o = t & 63, pg = t >> 6;   // pg is wave-uniform -> tmp reads broadcast
    float pob = po_b[o];
    for (int chunk=0; chunk<4; chunk++){
      int pixbase = pg*16 + chunk*4;
      float a0=0.f,a1=0.f,a2=0.f,a3=0.f;
      #pragma unroll
      for (int c4=0; c4<16; c4++){
        float w0v = s_pw[(c4*4+0)*65 + o];
        float w1v = s_pw[(c4*4+1)*65 + o];
        float w2v = s_pw[(c4*4+2)*65 + o];
        float w3v = s_pw[(c4*4+3)*65 + o];
        const float4 tA = *(const float4*)&s_tmp[(pixbase+0)*64 + c4*4];
        const float4 tB = *(const float4*)&s_tmp[(pixbase+1)*64 + c4*4];
        const float4 tC = *(const float4*)&s_tmp[(pixbase+2)*64 + c4*4];
        const float4 tD = *(const float4*)&s_tmp[(pixbase+3)*64 + c4*4];
        a0 += tA.x*w0v + tA.y*w1v + tA.z*w2v + tA.w*w3v;
        a1 += tB.x*w0v + tB.y*w1v + tB.z*w2v + tB.w*w3v;
        a2 += tC.x*w0v + tC.y*w1v + tC.z*w2v + tC.w*w3v;
        a3 += tD.x*w0v + tD.y*w1v + tD.z*w2v + tD.w*w3v;
      }
      float res[4] = {a0,a1,a2,a3};
      #pragma unroll
      for (int k=0;k<4;k++){
        int pix = pixbase + k;
        int hh = h0 + (pix>>3), wwp = w0 + (pix&7);
        out[(((size_t)b*NPIX + hh*96 + wwp)<<6) + o] = res[k] + pob;
      }
    }
  }
}

// ---------------------------------------------------------------------------
extern "C" void kernel_launch(void* const* d_in, const int* in_sizes, int n_in,
                              void* d_out, int out_size, void* d_ws, size_t ws_size,
                              hipStream_t stream) {
  const float* x        = (const float*)d_in[0];
  const float* se_w1    = (const float*)d_in[1];
  const float* se_b1    = (const float*)d_in[2];
  const float* se_w2    = (const float*)d_in[3];
  const float* se_b2    = (const float*)d_in[4];
  const float* dc_w     = (const float*)d_in[5];
  const float* dc_b     = (const float*)d_in[6];
  const float* l1_w     = (const float*)d_in[7];
  const float* l1_b     = (const float*)d_in[8];
  const float* l2_w     = (const float*)d_in[9];
  const float* l2_b     = (const float*)d_in[10];
  const float* gkf_w    = (const float*)d_in[11];
  const float* gkf_b    = (const float*)d_in[12];
  const float* fu_proj_w= (const float*)d_in[13];
  const float* fu_proj_b= (const float*)d_in[14];
  const float* fu_fc1_w = (const float*)d_in[15];
  const float* fu_fc1_b = (const float*)d_in[16];
  const float* fu_fc2_w = (const float*)d_in[17];
  const float* fu_fc2_b = (const float*)d_in[18];
  const float* fu_po_w  = (const float*)d_in[19];
  const float* fu_po_b  = (const float*)d_in[20];
  const float* po_w     = (const float*)d_in[21];
  const float* po_b     = (const float*)d_in[22];

  float* kern_ws = (float*)d_ws;              // 128*576 = 73728 floats
  float* kc_ws   = kern_ws + 73728;           // 32*576  = 18432 floats

  k_pool<<<1152, 256, 0, stream>>>(x, kern_ws);
  k_small<<<32, 256, 0, stream>>>(kern_ws, se_w1, se_b1, se_w2, se_b2,
                                  dc_w, dc_b, l1_w, l1_b, l2_w, l2_b,
                                  gkf_w, gkf_b, fu_proj_w, fu_proj_b,
                                  fu_fc1_w, fu_fc1_b, fu_fc2_w, fu_fc2_b,
                                  fu_po_w, fu_po_b, kc_ws);
  k_conv<<<4608, 256, 0, stream>>>(x, kc_ws, po_w, po_b, (float*)d_out);
}

// Round 3
// 242.167 us; speedup vs baseline: 1.5414x; 1.5414x over previous
//
#include <hip/hip_runtime.h>
#include <hip/hip_bf16.h>

// Static config: B=32, H=96, Wd=96, C=64, nW=4, K=3, WS=48, pool=16
#define NPIX 9216   // 96*96

typedef __attribute__((ext_vector_type(8))) short short8v;   // 8 bf16 (4 VGPRs)
typedef __attribute__((ext_vector_type(4))) float floatx4;   // 4 fp32

__device__ __forceinline__ float geluf(float x){
  return 0.5f * x * (1.0f + erff(x * 0.70710678118654752440f));
}
__device__ __forceinline__ float sigm(float x){
  return 1.0f / (1.0f + expf(-x));
}
__device__ __forceinline__ unsigned short f2bf(float f){
  __hip_bfloat16 h = __float2bfloat16(f);
  return *(unsigned short*)&h;
}

// ---------------------------------------------------------------------------
// Kernel A: windowed 48x48 -> 3x3 avg pool.  kern[bw=b*4+w][c][ki*3+kj]
// grid = 128 * 9 = 1152 blocks, 256 threads
// ---------------------------------------------------------------------------
__global__ __launch_bounds__(256) void k_pool(const float* __restrict__ x,
                                              float* __restrict__ kern)
{
  int blk = blockIdx.x;
  int bw = blk / 9, rem = blk % 9;          // rem = ki*3+kj
  int ki = rem / 3, kj = rem % 3;
  int b = bw >> 2, w = bw & 3;
  int wr = w >> 1, wc = w & 1;
  int t = threadIdx.x;
  int cg = t & 15, rw = t >> 4;             // cg: 4-channel group, rw: row 0..15
  int h = wr*48 + ki*16 + rw;
  int col0 = wc*48 + kj*16;
  size_t base = ((size_t)(b*NPIX + h*96 + col0))*64 + cg*4;
  float a0=0.f,a1=0.f,a2=0.f,a3=0.f;
  #pragma unroll
  for (int j=0;j<16;j++){
    float4 u = *(const float4*)(x + base + (size_t)j*64);
    a0 += u.x; a1 += u.y; a2 += u.z; a3 += u.w;
  }
  __shared__ float red[16*64];
  float* rr = &red[rw*64 + cg*4];
  rr[0]=a0; rr[1]=a1; rr[2]=a2; rr[3]=a3;
  __syncthreads();
  if (t < 64){
    float s = 0.f;
    #pragma unroll
    for (int r=0;r<16;r++) s += red[r*64 + t];
    kern[(size_t)bw*576 + t*9 + rem] = s * (1.0f/256.0f);
  }
}

// ---------------------------------------------------------------------------
// Kernel B: entire small graph per batch element -> combined 3x3 kernel
// kc[b][c][p] = 2*gkf + fu_po(x_sum).  grid = 32 blocks, 256 threads
// Block 0 additionally emits po_w in MFMA B-fragment order (bf16) for k_conv.
// ---------------------------------------------------------------------------
__global__ __launch_bounds__(256) void k_small(const float* __restrict__ kern_ws,
    const float* __restrict__ se_w1, const float* __restrict__ se_b1,
    const float* __restrict__ se_w2, const float* __restrict__ se_b2,
    const float* __restrict__ dc_w,  const float* __restrict__ dc_b,
    const float* __restrict__ l1_w,  const float* __restrict__ l1_b,
    const float* __restrict__ l2_w,  const float* __restrict__ l2_b,
    const float* __restrict__ gkf_w, const float* __restrict__ gkf_b,
    const float* __restrict__ fu_proj_w, const float* __restrict__ fu_proj_b,
    const float* __restrict__ fu_fc1_w,  const float* __restrict__ fu_fc1_b,
    const float* __restrict__ fu_fc2_w,  const float* __restrict__ fu_fc2_b,
    const float* __restrict__ fu_po_w,   const float* __restrict__ fu_po_b,
    const float* __restrict__ po_w,
    float* __restrict__ kc_ws,
    unsigned short* __restrict__ frag_pw)
{
  int b = blockIdx.x;
  int t = threadIdx.x;
  __shared__ float s_kern[4*64*9];   // [w][c][p]
  __shared__ float s_w[4096];        // transposed weight staging [i][o]
  __shared__ float s_tmp[4*64*9];    // gelu intermediate, later feats [g][o][p]
  __shared__ float s_kse[4*64*9];    // kern_se [w][c][p]
  __shared__ float s_wwc[256];       // [w][c]
  __shared__ float s_small[64];      // ww1(0..3), h1(16..31), ww2(32..35)
  __shared__ float s_gkf[576];       // [c][p]
  __shared__ float s_v0[256];
  __shared__ float s_v1[64];
  __shared__ float s_av[256];        // [w][c]
  __shared__ float s_xsum[576];      // [c][p]

  // block 0: write po_w as bf16 MFMA B-fragments.
  // frag id f = nb*2+kb; entry = f*512 + lane*8 + j  ->  B[k=c][n=o]
  // with o = nb*16 + (lane&15), c = kb*32 + (lane>>4)*8 + j
  if (b == 0){
    for (int idx=t; idx<4096; idx+=256){
      int f = idx >> 9, L = (idx >> 3) & 63, j = idx & 7;
      int nb = f >> 1, kb = f & 1;
      int o = nb*16 + (L & 15);
      int c = kb*32 + ((L >> 4) & 3)*8 + j;
      frag_pw[idx] = f2bf(po_w[o*64 + c]);
    }
  }

  for (int idx=t; idx<2304; idx+=256) s_kern[idx] = kern_ws[b*2304 + idx];
  for (int idx=t; idx<4096; idx+=256){ int o=idx>>6, i=idx&63; s_w[i*64+o] = se_w1[idx]; }
  __syncthreads();
  // SE layer 1: gelu(W1 @ kern + b1)
  for (int idx=t; idx<2304; idx+=256){
    int w = idx/576, rem = idx%576, o = rem/9, p = rem%9;
    float acc = se_b1[o];
    const float* kcol = &s_kern[w*576 + p];
    #pragma unroll 8
    for (int i=0;i<64;i++) acc += s_w[i*64+o]*kcol[i*9];
    s_tmp[idx] = geluf(acc);
  }
  __syncthreads();
  for (int idx=t; idx<4096; idx+=256){ int o=idx>>6, i=idx&63; s_w[i*64+o] = se_w2[idx]; }
  __syncthreads();
  // SE layer 2: sigmoid(W2 @ g + b2) -> kern_se
  for (int idx=t; idx<2304; idx+=256){
    int w = idx/576, rem = idx%576, o = rem/9, p = rem%9;
    float acc = se_b2[o];
    const float* gcol = &s_tmp[w*576 + p];
    #pragma unroll 8
    for (int i=0;i<64;i++) acc += s_w[i*64+o]*gcol[i*9];
    s_kse[idx] = sigm(acc);
  }
  __syncthreads();
  // window GAP == mean of the 9 kern entries (exact: pooling partitions window)
  { int w = t>>6, c = t&63; float s=0.f;
    #pragma unroll
    for (int p=0;p<9;p++) s += s_kern[w*576+c*9+p];
    s_wwc[t] = s*(1.0f/9.0f); }
  __syncthreads();
  if (t<4){ float acc = dc_b[t];
    for (int c=0;c<64;c++) acc += dc_w[t*64+c]*s_wwc[t*64+c];
    s_small[t]=acc; }
  __syncthreads();
  if (t<16){ float acc = l1_b[t];
    #pragma unroll
    for (int w=0;w<4;w++) acc += l1_w[t*4+w]*s_small[w];
    s_small[16+t]=geluf(acc); }
  __syncthreads();
  if (t<4){ float acc = l2_b[t];
    #pragma unroll
    for (int j=0;j<16;j++) acc += l2_w[t*16+j]*s_small[16+j];
    s_small[32+t]=sigm(acc); }
  __syncthreads();
  // gkf[c][p] = gkf_b[c] + sum_w gkf_w[c][w] * kse[w][c][p] * ww2[w]
  for (int idx=t; idx<576; idx+=256){
    int c = idx/9, p = idx%9;
    float acc = gkf_b[c];
    #pragma unroll
    for (int w=0;w<4;w++) acc += gkf_w[c*4+w]*s_kse[w*576+c*9+p]*s_small[32+w];
    s_gkf[idx] = acc;
  }
  // feats[g][o][p] = gelu(proj_b[g*4+o] + sum_i proj_w[g][o][i]*kse_flat[g*4+i][p])
  for (int idx=t; idx<2304; idx+=256){
    int g = idx/36, rem = idx%36, o = rem/9, p = rem%9;
    float acc = fu_proj_b[g*4+o];
    #pragma unroll
    for (int i=0;i<4;i++){
      int ch = g*4+i;                       // flat channel in (w*C + c) layout
      acc += fu_proj_w[(g*4+o)*4+i] * s_kse[(ch>>6)*576 + (ch&63)*9 + p];
    }
    s_tmp[idx] = geluf(acc);
  }
  __syncthreads();
  // v0[m] = mean_p feats
  { float s=0.f;
    #pragma unroll
    for (int p=0;p<9;p++) s += s_tmp[t*9+p];
    s_v0[t] = s*(1.0f/9.0f); }
  __syncthreads();
  if (t<64){ float acc = fu_fc1_b[t];
    for (int k=0;k<256;k++) acc += fu_fc1_w[t*256+k]*s_v0[k];
    s_v1[t]=geluf(acc); }
  __syncthreads();
  { float acc = fu_fc2_b[t];
    #pragma unroll 8
    for (int o2=0;o2<64;o2++) acc += fu_fc2_w[t*64+o2]*s_v1[o2];
    s_av[t]=acc; }
  __syncthreads();
  if (t<64){
    float z0=s_av[t], z1=s_av[64+t], z2=s_av[128+t], z3=s_av[192+t];
    float mx = fmaxf(fmaxf(z0,z1),fmaxf(z2,z3));
    float e0=expf(z0-mx), e1=expf(z1-mx), e2=expf(z2-mx), e3=expf(z3-mx);
    float inv = 1.0f/(e0+e1+e2+e3);
    s_av[t]=e0*inv; s_av[64+t]=e1*inv; s_av[128+t]=e2*inv; s_av[192+t]=e3*inv;
  }
  __syncthreads();
  for (int idx=t; idx<576; idx+=256){
    int c=idx/9, p=idx%9; float s=0.f;
    #pragma unroll
    for (int w=0;w<4;w++) s += s_kse[w*576+c*9+p]*s_av[w*64+c];
    s_xsum[idx]=s;
  }
  __syncthreads();
  // combined kernel kc = gkf + gks = 2*gkf + fu_po_w @ x_sum + fu_po_b
  for (int idx=t; idx<576; idx+=256){
    int c=idx/9, p=idx%9;
    float acc = 2.0f*s_gkf[idx] + fu_po_b[c];
    #pragma unroll 8
    for (int i=0;i<64;i++) acc += fu_po_w[c*64+i]*s_xsum[i*9+p];
    kc_ws[b*576+idx] = acc;
  }
}

// ---------------------------------------------------------------------------
// Kernel C: depthwise 3x3 (per b,c kernel kc) + MFMA 64x64x64 conv1x1
// grid = 32 * 144 = 4608 blocks (8x8 pixel tile each), 256 threads
// LDS: s_x 25.6K + s_tmp 9.2K + s_kc 2.3K ~= 37.1 KB -> 4 blocks/CU
// ---------------------------------------------------------------------------
__global__ __launch_bounds__(256, 4) void k_conv(const float* __restrict__ x,
                                                 const float* __restrict__ kc_ws,
                                                 const unsigned short* __restrict__ frag_pw,
                                                 const float* __restrict__ po_b,
                                                 float* __restrict__ out)
{
  int bi = blockIdx.x;
  int b = bi / 144, tile = bi % 144;
  int th = tile / 12, tw = tile % 12;
  int h0 = th*8, w0 = tw*8;
  int t = threadIdx.x;

  __shared__ float s_x[100*64];              // halo tile [r*10+col][c]
  __shared__ unsigned short s_tmp[64*72];    // depthwise result bf16, [px][c] stride 72
  __shared__ float s_kc[576];                // [c][p]

  // stage x halo tile (10x10 pixels, zero-padded at image edges)
  for (int idx=t; idx<1600; idx+=256){
    int pix = idx >> 4, c4 = idx & 15;
    int r = pix / 10, col = pix % 10;
    int hh = h0 - 1 + r, ww = w0 - 1 + col;
    float4 v = make_float4(0.f,0.f,0.f,0.f);
    if (hh >= 0 && hh < 96 && ww >= 0 && ww < 96)
      v = *(const float4*)(x + (((size_t)b*NPIX + hh*96 + ww)<<6) + c4*4);
    *(float4*)&s_x[pix*64 + c4*4] = v;
  }
  for (int idx=t; idx<576; idx+=256) s_kc[idx] = kc_ws[b*576 + idx];
  __syncthreads();

  // phase 1: depthwise 3x3, register sliding window.
  // thread = (c = t&63, rg = t>>6); computes pixel rows 2rg, 2rg+1 (8 cols each)
  {
    int c = t & 63, rg = t >> 6;
    int r0 = rg*2;
    float k0=s_kc[c*9+0],k1=s_kc[c*9+1],k2=s_kc[c*9+2],
          k3=s_kc[c*9+3],k4=s_kc[c*9+4],k5=s_kc[c*9+5],
          k6=s_kc[c*9+6],k7=s_kc[c*9+7],k8=s_kc[c*9+8];
    float row[4][10];
    #pragma unroll
    for (int rr=0; rr<4; rr++)
      #pragma unroll
      for (int cc=0; cc<10; cc++)
        row[rr][cc] = s_x[((r0+rr)*10 + cc)*64 + c];   // s_x row r0+rr = pixel row r0+rr-1
    #pragma unroll
    for (int dr=0; dr<2; dr++){
      int pr = r0 + dr;
      #pragma unroll
      for (int pc=0; pc<8; pc++){
        float acc = k0*row[dr+0][pc] + k1*row[dr+0][pc+1] + k2*row[dr+0][pc+2]
                  + k3*row[dr+1][pc] + k4*row[dr+1][pc+1] + k5*row[dr+1][pc+2]
                  + k6*row[dr+2][pc] + k7*row[dr+2][pc+1] + k8*row[dr+2][pc+2];
        s_tmp[(pr*8 + pc)*72 + c] = f2bf(acc);
      }
    }
  }
  __syncthreads();

  // phase 2: out[px][o] = tmp[px][c] @ po_wT[c][o] + po_b  via MFMA 16x16x32 bf16
  {
    int wv = t >> 6, lane = t & 63;
    int m = wv*16 + (lane & 15);          // pixel row index of this lane's A rows
    int quad = lane >> 4;
    floatx4 acc[4] = {{0.f,0.f,0.f,0.f},{0.f,0.f,0.f,0.f},
                      {0.f,0.f,0.f,0.f},{0.f,0.f,0.f,0.f}};
    #pragma unroll
    for (int kb=0; kb<2; kb++){
      short8v afrag = *(const short8v*)&s_tmp[m*72 + kb*32 + quad*8];
      #pragma unroll
      for (int nb=0; nb<4; nb++){
        short8v bfrag = *(const short8v*)(frag_pw + (nb*2+kb)*512 + lane*8);
        acc[nb] = __builtin_amdgcn_mfma_f32_16x16x32_bf16(afrag, bfrag, acc[nb], 0, 0, 0);
      }
    }
    // D layout: col = lane&15 (o within nb), row = quad*4 + reg (px within wave's 16)
    #pragma unroll
    for (int nb=0; nb<4; nb++){
      int o = nb*16 + (lane & 15);
      float pb = po_b[o];
      #pragma unroll
      for (int r=0; r<4; r++){
        int px = wv*16 + quad*4 + r;
        int hh = h0 + (px >> 3), wwp = w0 + (px & 7);
        out[(((size_t)b*NPIX + hh*96 + wwp)<<6) + o] = acc[nb][r] + pb;
      }
    }
  }
}

// ---------------------------------------------------------------------------
extern "C" void kernel_launch(void* const* d_in, const int* in_sizes, int n_in,
                              void* d_out, int out_size, void* d_ws, size_t ws_size,
                              hipStream_t stream) {
  const float* x        = (const float*)d_in[0];
  const float* se_w1    = (const float*)d_in[1];
  const float* se_b1    = (const float*)d_in[2];
  const float* se_w2    = (const float*)d_in[3];
  const float* se_b2    = (const float*)d_in[4];
  const float* dc_w     = (const float*)d_in[5];
  const float* dc_b     = (const float*)d_in[6];
  const float* l1_w     = (const float*)d_in[7];
  const float* l1_b     = (const float*)d_in[8];
  const float* l2_w     = (const float*)d_in[9];
  const float* l2_b     = (const float*)d_in[10];
  const float* gkf_w    = (const float*)d_in[11];
  const float* gkf_b    = (const float*)d_in[12];
  const float* fu_proj_w= (const float*)d_in[13];
  const float* fu_proj_b= (const float*)d_in[14];
  const float* fu_fc1_w = (const float*)d_in[15];
  const float* fu_fc1_b = (const float*)d_in[16];
  const float* fu_fc2_w = (const float*)d_in[17];
  const float* fu_fc2_b = (const float*)d_in[18];
  const float* fu_po_w  = (const float*)d_in[19];
  const float* fu_po_b  = (const float*)d_in[20];
  const float* po_w     = (const float*)d_in[21];
  const float* po_b     = (const float*)d_in[22];

  float* kern_ws = (float*)d_ws;                       // 128*576 = 73728 floats
  float* kc_ws   = kern_ws + 73728;                    // 32*576  = 18432 floats
  unsigned short* frag_pw = (unsigned short*)(kc_ws + 18432);  // 4096 ushort (8 KB), 16B-aligned

  k_pool<<<1152, 256, 0, stream>>>(x, kern_ws);
  k_small<<<32, 256, 0, stream>>>(kern_ws, se_w1, se_b1, se_w2, se_b2,
                                  dc_w, dc_b, l1_w, l1_b, l2_w, l2_b,
                                  gkf_w, gkf_b, fu_proj_w, fu_proj_b,
                                  fu_fc1_w, fu_fc1_b, fu_fc2_w, fu_fc2_b,
                                  fu_po_w, fu_po_b, po_w, kc_ws, frag_pw);
  k_conv<<<4608, 256, 0, stream>>>(x, kc_ws, frag_pw, po_b, (float*)d_out);
}